// Round 10
// baseline (106.713 us; speedup 1.0000x reference)
//
#include <hip/hip_runtime.h>

#define TPB 512

// ---- verified compute core (R7/R9): 28 outputs, all-b128 LDS reads ----
__device__ __forceinline__ void compute28(const float4* __restrict__ sm4,
                                          const float wt[3][2][3],
                                          int j, int pl, int q0, int qb, int h,
                                          float acc[28]) {
#pragma unroll
    for (int u = 0; u < 28; ++u) acc[u] = 0.f;
#pragma unroll
    for (int i = 0; i < 3; ++i) {
        const int g = j + i - 1;
        if ((unsigned)g < 32u) {
#pragma unroll
            for (int m = 0; m < 2; ++m) {
                const float4* row4 = &sm4[((2 * g + m) * 2 + pl) * 15];
                float fe[32];
                { const float4 t = row4[q0]; fe[0] = t.x; fe[1] = t.y; fe[2] = t.z; fe[3] = t.w; }
#pragma unroll
                for (int q = 1; q < 8; ++q) {
                    const float4 t = row4[qb + q];
                    fe[4 * q + 0] = t.x; fe[4 * q + 1] = t.y;
                    fe[4 * q + 2] = t.z; fe[4 * q + 3] = t.w;
                }
                float va[30];
#pragma unroll
                for (int d = 0; d < 30; ++d) va[d] = fe[d + 2];
                va[0]  = h ? va[0] : 0.f;
                va[29] = h ? 0.f : va[29];
                const float w0 = wt[i][m][0];
                const float w1 = wt[i][m][1];
                const float w2 = wt[i][m][2];
#pragma unroll
                for (int u = 0; u < 28; ++u)
                    acc[u] += w0 * va[u] + w1 * va[u + 1] + w2 * va[u + 2];
            }
        }
    }
}

// ---- verified 2-pass transposed store (R9), parameterized by n ----
__device__ __forceinline__ void store2(float4* __restrict__ sm4, float4* __restrict__ o4,
                                       const float acc[28], int tid, int c, int h, int pl,
                                       int n, int p0) {
    const int chalf = c >> 6;
    const int cr = c & 63;
#pragma unroll
    for (int half = 0; half < 2; ++half) {
        __syncthreads();             // compute/staging reads or previous pass reads done
        if (chalf == half) {
#pragma unroll
            for (int u4 = 0; u4 < 7; ++u4) {
                float4 v4;
                v4.x = acc[4 * u4 + 0];
                v4.y = acc[4 * u4 + 1];
                v4.z = acc[4 * u4 + 2];
                v4.w = acc[4 * u4 + 3];
                sm4[(cr + 64 * pl) * 15 + h * 7 + u4] = v4;
            }
        }
        __syncthreads();
#pragma unroll
        for (int it = 0; it < 4; ++it) {
            const int idx = tid + it * TPB;
            if (idx < 1792) {
                const int chp = idx / 14;
                const int v = idx - chp * 14;
                const int scr = chp & 63;
                const int spl = chp >> 6;
                o4[(size_t)(n * 128 + half * 64 + scr) * 784 + (size_t)(p0 + spl) * 14 + (size_t)v] =
                    sm4[chp * 15 + v];
            }
        }
    }
}

__global__ __launch_bounds__(TPB) void fused_shift_conv(const float* __restrict__ x,
                                                        const float* __restrict__ Wg,
                                                        float* __restrict__ out) {
    // block handles TWO tiles: (n0, p0..p0+1) and (n0+1, p0..p0+1)
    const int bid = blockIdx.x;
    const int ptile = bid % 28;
    const int n0 = (bid / 28) * 2;
    const int p0 = ptile * 2;
    const int P0 = (p0 + 55) % 56;   // source row for output p0   (roll +1 along p)
    const int P1 = p0;               // source row for output p0+1

    __shared__ float4 sm4[128 * 15]; // 30,720 B: staging rows S=2r+q; store rows cr+64*pl

    const int tid = threadIdx.x;
    const int pl = tid >> 8;
    const int t8 = tid & 255;
    const int h = t8 & 1;
    const int c = t8 >> 1;
    const int j = c >> 2;
    const int k = c & 3;
    const int q0 = h ? 6 : 13;
    const int qb = h ? 6 : -1;

    // ---- W loads first (amortized over both tiles) ----
    float wt[3][2][3];
#pragma unroll
    for (int i = 0; i < 3; ++i)
#pragma unroll
        for (int m = 0; m < 2; ++m)
#pragma unroll
            for (int l = 0; l < 3; ++l)
                wt[i][m][l] = Wg[(((j * 3 + i) * 2 + m) * 3 + l) * 4 + k];

    const float4* x4 = reinterpret_cast<const float4*>(x);

    // ---- stage tile0: load pair, sum, ds_write ----
#pragma unroll
    for (int it = 0; it < 4; ++it) {
        const int idx = tid + it * TPB;
        if (idx < 1792) {
            const int S = idx / 14;
            const int v = idx - S * 14;
            const int r = S >> 1;
            const int q = S & 1;
            const int Pq = q ? P1 : P0;
            const size_t base = (size_t)(n0 * 128 + r) * 784 + (size_t)Pq * 14 + (size_t)v;
            const float4 a = x4[base];
            const float4 b = x4[base + (size_t)64 * 784];
            float4 s;
            s.x = a.x + b.x; s.y = a.y + b.y; s.z = a.z + b.z; s.w = a.w + b.w;
            sm4[S * 15 + v] = s;
        }
    }

    // ---- prefetch tile1 (n0+1): issue loads NOW, consume after compute0 ----
    float4 pa[4], pb[4];
#pragma unroll
    for (int it = 0; it < 4; ++it) {
        const int idx = tid + it * TPB;
        if (idx < 1792) {
            const int S = idx / 14;
            const int v = idx - S * 14;
            const int r = S >> 1;
            const int q = S & 1;
            const int Pq = q ? P1 : P0;
            const size_t base = (size_t)((n0 + 1) * 128 + r) * 784 + (size_t)Pq * 14 + (size_t)v;
            pa[it] = x4[base];
            pb[it] = x4[base + (size_t)64 * 784];
        }
    }

    __syncthreads();                 // B1: tile0 staged

    float acc[28];
    compute28(sm4, wt, j, pl, q0, qb, h, acc);

    // fold prefetch into sums (frees pb; vmcnt waits land here, after compute0)
#pragma unroll
    for (int it = 0; it < 4; ++it) {
        const int idx = tid + it * TPB;
        if (idx < 1792) {
            pa[it].x += pb[it].x; pa[it].y += pb[it].y;
            pa[it].z += pb[it].z; pa[it].w += pb[it].w;
        }
    }

    float4* o4 = reinterpret_cast<float4*>(out);
    store2(sm4, o4, acc, tid, c, h, pl, n0, p0);   // B2..B5 inside

    __syncthreads();                 // B6: store0 pass-2 reads done -> buffer free

    // ---- stage tile1 from registers (no loads, no stall) ----
#pragma unroll
    for (int it = 0; it < 4; ++it) {
        const int idx = tid + it * TPB;
        if (idx < 1792) {
            const int S = idx / 14;
            const int v = idx - S * 14;
            sm4[S * 15 + v] = pa[it];
        }
    }
    __syncthreads();                 // B7: tile1 staged

    compute28(sm4, wt, j, pl, q0, qb, h, acc);
    store2(sm4, o4, acc, tid, c, h, pl, n0 + 1, p0);  // B8..B11 inside
}

extern "C" void kernel_launch(void* const* d_in, const int* in_sizes, int n_in,
                              void* d_out, int out_size, void* d_ws, size_t ws_size,
                              hipStream_t stream) {
    const float* x = (const float*)d_in[0];
    const float* W = (const float*)d_in[1];
    float* out = (float*)d_out;
    const int n = in_sizes[0] / (128 * 56 * 56);   // 128
    const int grid = (n / 2) * 28;                  // one block per (n-pair, 2-row p-tile)
    fused_shift_conv<<<grid, TPB, 0, stream>>>(x, W, out);
}

// Round 11
// 101.403 us; speedup vs baseline: 1.0524x; 1.0524x over previous
//
#include <hip/hip_runtime.h>

#define TPB 512
#define PT  7   // 2-row p-tiles per block (28 / 4)

// ---- verified compute core (R7/R9): 28 outputs, all-b128 LDS reads ----
__device__ __forceinline__ void compute28(const float4* __restrict__ sm4,
                                          const float wt[3][2][3],
                                          int j, int pl, int q0, int qb, int h,
                                          float acc[28]) {
#pragma unroll
    for (int u = 0; u < 28; ++u) acc[u] = 0.f;
#pragma unroll
    for (int i = 0; i < 3; ++i) {
        const int g = j + i - 1;
        if ((unsigned)g < 32u) {
#pragma unroll
            for (int m = 0; m < 2; ++m) {
                const float4* row4 = &sm4[((2 * g + m) * 2 + pl) * 15];
                float fe[32];
                { const float4 t = row4[q0]; fe[0] = t.x; fe[1] = t.y; fe[2] = t.z; fe[3] = t.w; }
#pragma unroll
                for (int q = 1; q < 8; ++q) {
                    const float4 t = row4[qb + q];
                    fe[4 * q + 0] = t.x; fe[4 * q + 1] = t.y;
                    fe[4 * q + 2] = t.z; fe[4 * q + 3] = t.w;
                }
                float va[30];
#pragma unroll
                for (int d = 0; d < 30; ++d) va[d] = fe[d + 2];
                va[0]  = h ? va[0] : 0.f;
                va[29] = h ? 0.f : va[29];
                const float w0 = wt[i][m][0];
                const float w1 = wt[i][m][1];
                const float w2 = wt[i][m][2];
#pragma unroll
                for (int u = 0; u < 28; ++u)
                    acc[u] += w0 * va[u] + w1 * va[u + 1] + w2 * va[u + 2];
            }
        }
    }
}

// ---- verified 2-pass transposed store (R9) ----
__device__ __forceinline__ void store2(float4* __restrict__ sm4, float4* __restrict__ o4,
                                       const float acc[28], int tid, int c, int h, int pl,
                                       int n, int p0) {
    const int chalf = c >> 6;
    const int cr = c & 63;
#pragma unroll
    for (int half = 0; half < 2; ++half) {
        __syncthreads();             // compute reads (pass0) / pass-1 reads (pass1) done
        if (chalf == half) {
#pragma unroll
            for (int u4 = 0; u4 < 7; ++u4) {
                float4 v4;
                v4.x = acc[4 * u4 + 0];
                v4.y = acc[4 * u4 + 1];
                v4.z = acc[4 * u4 + 2];
                v4.w = acc[4 * u4 + 3];
                sm4[(cr + 64 * pl) * 15 + h * 7 + u4] = v4;
            }
        }
        __syncthreads();
#pragma unroll
        for (int it = 0; it < 4; ++it) {
            const int idx = tid + it * TPB;
            if (idx < 1792) {
                const int chp = idx / 14;
                const int v = idx - chp * 14;
                const int scr = chp & 63;
                const int spl = chp >> 6;
                o4[(size_t)(n * 128 + half * 64 + scr) * 784 + (size_t)(p0 + spl) * 14 + (size_t)v] =
                    sm4[chp * 15 + v];
            }
        }
    }
}

__global__ __launch_bounds__(TPB) void fused_shift_conv(const float* __restrict__ x,
                                                        const float* __restrict__ Wg,
                                                        float* __restrict__ out) {
    // block = (n, quarter): handles 7 consecutive 2-row p-tiles of one image
    const int bid = blockIdx.x;
    const int quarter = bid & 3;
    const int n = bid >> 2;
    const int pt0 = quarter * PT;

    __shared__ float4 smA[128 * 15];   // 30,720 B each; double buffer
    __shared__ float4 smB[128 * 15];

    const int tid = threadIdx.x;
    const int pl = tid >> 8;
    const int t8 = tid & 255;
    const int h = t8 & 1;
    const int c = t8 >> 1;
    const int j = c >> 2;
    const int k = c & 3;
    const int q0 = h ? 6 : 13;
    const int qb = h ? 6 : -1;

    // per-thread staging slot (constant across tiles)
    const int sidx = tid < 448 ? -1 : 0;   // dummy to keep pattern simple (unused)
    (void)sidx;

    // ---- W loads once per block (amortized over 7 tiles) ----
    float wt[3][2][3];
#pragma unroll
    for (int i = 0; i < 3; ++i)
#pragma unroll
        for (int m = 0; m < 2; ++m)
#pragma unroll
            for (int l = 0; l < 3; ++l)
                wt[i][m][l] = Wg[(((j * 3 + i) * 2 + m) * 3 + l) * 4 + k];

    const float4* x4 = reinterpret_cast<const float4*>(x);
    float4* o4 = reinterpret_cast<float4*>(out);

    // ---- prologue: stage tile 0 into smA ----
    {
        const int p0 = (pt0) * 2;
        const int P0 = (p0 + 55) % 56;
        const int P1 = p0;
#pragma unroll
        for (int it = 0; it < 4; ++it) {
            const int idx = tid + it * TPB;
            if (idx < 1792) {
                const int S = idx / 14;
                const int v = idx - S * 14;
                const int r = S >> 1;
                const int q = S & 1;
                const int Pq = q ? P1 : P0;
                const size_t base = (size_t)(n * 128 + r) * 784 + (size_t)Pq * 14 + (size_t)v;
                const float4 a = x4[base];
                const float4 b = x4[base + (size_t)64 * 784];
                float4 s;
                s.x = a.x + b.x; s.y = a.y + b.y; s.z = a.z + b.z; s.w = a.w + b.w;
                smA[S * 15 + v] = s;
            }
        }
    }

    float4* bcur = smA;
    float4* bnxt = smB;

#pragma unroll 1
    for (int t = 0; t < PT; ++t) {
        const int p0 = (pt0 + t) * 2;

        // ---- issue prefetch of tile t+1 (regs); in flight across compute+store ----
        float4 pa[4], pb[4];
        const bool more = (t + 1 < PT);
        if (more) {
            const int p0n = (pt0 + t + 1) * 2;
            const int P0n = (p0n + 55) % 56;
            const int P1n = p0n;
#pragma unroll
            for (int it = 0; it < 4; ++it) {
                const int idx = tid + it * TPB;
                if (idx < 1792) {
                    const int S = idx / 14;
                    const int v = idx - S * 14;
                    const int r = S >> 1;
                    const int q = S & 1;
                    const int Pq = q ? P1n : P0n;
                    const size_t base = (size_t)(n * 128 + r) * 784 + (size_t)Pq * 14 + (size_t)v;
                    pa[it] = x4[base];
                    pb[it] = x4[base + (size_t)64 * 784];
                }
            }
        }

        __syncthreads();               // bcur fully staged (prologue or previous iter)

        float acc[28];
        compute28(bcur, wt, j, pl, q0, qb, h, acc);

        store2(bcur, o4, acc, tid, c, h, pl, n, p0);   // 4 barriers inside

        if (more) {
            // fold prefetch (vmcnt waits land here, after compute+store issue)
#pragma unroll
            for (int it = 0; it < 4; ++it) {
                const int idx = tid + it * TPB;
                if (idx < 1792) {
                    const int S = idx / 14;
                    const int v = idx - S * 14;
                    float4 s;
                    s.x = pa[it].x + pb[it].x;
                    s.y = pa[it].y + pb[it].y;
                    s.z = pa[it].z + pb[it].z;
                    s.w = pa[it].w + pb[it].w;
                    bnxt[S * 15 + v] = s;
                }
            }
        }

        float4* tmp = bcur; bcur = bnxt; bnxt = tmp;
    }
}

extern "C" void kernel_launch(void* const* d_in, const int* in_sizes, int n_in,
                              void* d_out, int out_size, void* d_ws, size_t ws_size,
                              hipStream_t stream) {
    const float* x = (const float*)d_in[0];
    const float* W = (const float*)d_in[1];
    float* out = (float*)d_out;
    const int n = in_sizes[0] / (128 * 56 * 56);   // 128
    const int grid = n * 4;                         // (n, quarter) ; 7 tiles per block
    fused_shift_conv<<<grid, TPB, 0, stream>>>(x, W, out);
}